// Round 1
// baseline (852.046 us; speedup 1.0000x reference)
//
#include <hip/hip_runtime.h>

#define N_NODES 50000
#define N_EDGES 800000
#define D 128
#define BN_EPS 1e-5f

// ---------------- workspace layout (bytes) ----------------
// cnt_in   @ 0        (200000)
// cnt_out  @ 262144   (200000)
// row_ptr  @ 524288   (200004)
// cursor   @ 786432   (200000)
// rin      @ 1048576  (200000)
// rout     @ 1310720  (200000)
// bn_part  @ 1572864  (1024: sum[128], sumsq[128])
// scsh     @ 1576960  (1024: scale[128], shift[128])
// Wt       @ 1581056  (65536)
// Wrt      @ 1646592  (65536)
// csr_src  @ 1712128  (3200000)
// hw       @ 4912128  (25600000)   total ~30.5 MB

__global__ void zero_kernel(int* __restrict__ a, int* __restrict__ b, float* __restrict__ c) {
    int i = blockIdx.x * blockDim.x + threadIdx.x;
    if (i < N_NODES) { a[i] = 0; b[i] = 0; }
    if (i < 256) c[i] = 0.f;
}

__global__ void deg_kernel(const int* __restrict__ src, const int* __restrict__ dst,
                           int* __restrict__ cnt_out, int* __restrict__ cnt_in) {
    int e = blockIdx.x * blockDim.x + threadIdx.x;
    if (e < N_EDGES) {
        atomicAdd(&cnt_out[src[e]], 1);
        atomicAdd(&cnt_in[dst[e]], 1);
    }
}

// single-block exclusive scan of cnt_in -> row_ptr (+cursor copy), plus rsqrt norms
__global__ __launch_bounds__(1024) void scan_kernel(
        const int* __restrict__ cnt_in, const int* __restrict__ cnt_out,
        int* __restrict__ row_ptr, int* __restrict__ cursor,
        float* __restrict__ rin, float* __restrict__ rout) {
    __shared__ int part[1024];
    int t = threadIdx.x;
    const int C = (N_NODES + 1023) / 1024;   // 49
    int begin = t * C;
    int end = begin + C; if (end > N_NODES) end = N_NODES; if (begin > N_NODES) begin = N_NODES;
    int s = 0;
    for (int i = begin; i < end; i++) s += cnt_in[i];
    part[t] = s;
    __syncthreads();
    for (int off = 1; off < 1024; off <<= 1) {
        int v = (t >= off) ? part[t - off] : 0;
        __syncthreads();
        part[t] += v;
        __syncthreads();
    }
    int run = (t == 0) ? 0 : part[t - 1];
    for (int i = begin; i < end; i++) {
        row_ptr[i] = run;
        cursor[i]  = run;
        int cv = cnt_in[i];
        rin[i] = rsqrtf((float)(cv > 1 ? cv : 1));
        run += cv;
    }
    if (t == 1023) row_ptr[N_NODES] = run;   // == N_EDGES
    for (int i = t; i < N_NODES; i += 1024) {
        int cv = cnt_out[i];
        rout[i] = rsqrtf((float)(cv > 1 ? cv : 1));
    }
}

__global__ void fill_kernel(const int* __restrict__ src, const int* __restrict__ dst,
                            int* __restrict__ cursor, int* __restrict__ csr_src) {
    int e = blockIdx.x * blockDim.x + threadIdx.x;
    if (e < N_EDGES) {
        int d = dst[e];
        int p = atomicAdd(&cursor[d], 1);
        csr_src[p] = src[e];
    }
}

// W,Wr are [k][c]; store transposed [c][k] so per-column reads are contiguous
// (enables wave-uniform scalar s_load batches in gemm_kernel).
__global__ void transpose_kernel(const float* __restrict__ W, const float* __restrict__ Wr,
                                 float* __restrict__ Wt, float* __restrict__ Wrt) {
    int i = blockIdx.x * blockDim.x + threadIdx.x;
    if (i < D * D) {
        int k = i >> 7, c = i & 127;
        Wt[c * D + k]  = W[k * D + c];
        Wrt[c * D + k] = Wr[k * D + c];
    }
}

// Dual GEMM: hw = rout[r] * (x[r] @ W)   (pre-aggregation, no bias/relu yet)
//            res = relu(x[r] @ Wr + br)  -> written into d_out
// Layout: lane -> row within 64-row group; wave -> (row-group, column-half).
// x row lives in 128 VGPRs; W columns are wave-uniform -> scalar loads.
__global__ __launch_bounds__(256) void gemm_kernel(
        const float* __restrict__ x,
        const float* __restrict__ Wt, const float* __restrict__ Wrt,
        const float* __restrict__ br, const float* __restrict__ rout,
        float* __restrict__ hw, float* __restrict__ res) {
    int lane = threadIdx.x & 63;
    int gw = blockIdx.x * (blockDim.x >> 6) + (threadIdx.x >> 6);
    int half = __builtin_amdgcn_readfirstlane(gw & 1);
    int rg   = __builtin_amdgcn_readfirstlane(gw >> 1);
    int r = rg * 64 + lane;
    if (r >= N_NODES) return;
    float xr[D];
    const float4* xv = (const float4*)(x + (size_t)r * D);
    #pragma unroll
    for (int i = 0; i < D / 4; i++) {
        float4 v = xv[i];
        xr[4*i] = v.x; xr[4*i+1] = v.y; xr[4*i+2] = v.z; xr[4*i+3] = v.w;
    }
    float ro = rout[r];
    const int c0 = half * 64;
    for (int c = c0; c < c0 + 64; c++) {
        float acc = 0.f, accr = 0.f;
        #pragma unroll
        for (int k = 0; k < D; k++) {
            acc  += xr[k] * Wt[c * D + k];
            accr += xr[k] * Wrt[c * D + k];
        }
        hw[r * D + c]  = ro * acc;
        res[r * D + c] = fmaxf(accr + br[c], 0.f);
    }
}

// Per-dst aggregation over CSR, fused with bias/relu, residual add and BN partial stats.
// One wave per node (strided); lane owns columns {2*lane, 2*lane+1} as a float2.
__global__ __launch_bounds__(256) void agg_kernel(
        const float* __restrict__ hw, const int* __restrict__ row_ptr,
        const int* __restrict__ csr_src, const float* __restrict__ rin,
        const float* __restrict__ bias, float* __restrict__ y,
        float* __restrict__ bn_part) {
    int lane = threadIdx.x & 63;
    int wave = blockIdx.x * (blockDim.x >> 6) + (threadIdx.x >> 6);
    int nw = gridDim.x * (blockDim.x >> 6);
    float b0 = bias[2 * lane], b1 = bias[2 * lane + 1];
    float s10 = 0.f, s11 = 0.f, s20 = 0.f, s21 = 0.f;
    for (int n = wave; n < N_NODES; n += nw) {
        int e0 = row_ptr[n], e1 = row_ptr[n + 1];
        float a0 = 0.f, a1 = 0.f;
        for (int j0 = e0; j0 < e1; j0 += 64) {
            int myidx = (j0 + lane < e1) ? csr_src[j0 + lane] : 0;
            int cnt = e1 - j0; if (cnt > 64) cnt = 64;
            for (int i = 0; i < cnt; i++) {
                int sIdx = __builtin_amdgcn_readlane(myidx, i);   // SGPR -> saddr loads
                const float2 v = *((const float2*)(hw + sIdx * D) + lane);
                a0 += v.x; a1 += v.y;
            }
        }
        float ri = rin[n];
        float2 rv = *((const float2*)(y + n * D) + lane);        // residual (from gemm)
        float y0 = fmaxf(a0 * ri + b0, 0.f) + rv.x;
        float y1 = fmaxf(a1 * ri + b1, 0.f) + rv.y;
        *((float2*)(y + n * D) + lane) = make_float2(y0, y1);
        s10 += y0; s11 += y1; s20 += y0 * y0; s21 += y1 * y1;
    }
    atomicAdd(&bn_part[2 * lane],       s10);
    atomicAdd(&bn_part[2 * lane + 1],   s11);
    atomicAdd(&bn_part[128 + 2 * lane],     s20);
    atomicAdd(&bn_part[128 + 2 * lane + 1], s21);
}

__global__ void bn_fin(const float* __restrict__ bn_part, const float* __restrict__ gamma,
                       const float* __restrict__ beta, float* __restrict__ scsh) {
    int c = threadIdx.x;
    if (c < D) {
        const float invN = 1.0f / (float)N_NODES;
        float mean = bn_part[c] * invN;
        float var  = bn_part[128 + c] * invN - mean * mean;
        float sc = gamma[c] * rsqrtf(var + BN_EPS);
        scsh[c] = sc;
        scsh[128 + c] = beta[c] - mean * sc;
    }
}

__global__ void norm_kernel(float* __restrict__ y, const float* __restrict__ scsh) {
    int i = blockIdx.x * blockDim.x + threadIdx.x;   // float2 index
    if (i < N_NODES * 64) {
        float2 v = ((float2*)y)[i];
        int c = (i & 63) * 2;
        v.x = v.x * scsh[c]     + scsh[128 + c];
        v.y = v.y * scsh[c + 1] + scsh[128 + c + 1];
        ((float2*)y)[i] = v;
    }
}

extern "C" void kernel_launch(void* const* d_in, const int* in_sizes, int n_in,
                              void* d_out, int out_size, void* d_ws, size_t ws_size,
                              hipStream_t stream) {
    const float* x     = (const float*)d_in[0];
    const int*   src   = (const int*)d_in[1];
    const int*   dst   = (const int*)d_in[2];
    const float* W     = (const float*)d_in[3];
    const float* b     = (const float*)d_in[4];
    const float* Wr    = (const float*)d_in[5];
    const float* br    = (const float*)d_in[6];
    const float* gamma = (const float*)d_in[7];
    const float* beta  = (const float*)d_in[8];
    float* out = (float*)d_out;

    char* ws = (char*)d_ws;
    int*   cnt_in  = (int*)(ws + 0);
    int*   cnt_out = (int*)(ws + 262144);
    int*   row_ptr = (int*)(ws + 524288);
    int*   cursor  = (int*)(ws + 786432);
    float* rin     = (float*)(ws + 1048576);
    float* rout    = (float*)(ws + 1310720);
    float* bn_part = (float*)(ws + 1572864);
    float* scsh    = (float*)(ws + 1576960);
    float* Wt      = (float*)(ws + 1581056);
    float* Wrt     = (float*)(ws + 1646592);
    int*   csr_src = (int*)(ws + 1712128);
    float* hw      = (float*)(ws + 4912128);

    zero_kernel<<<(N_NODES + 255) / 256, 256, 0, stream>>>(cnt_in, cnt_out, bn_part);
    deg_kernel<<<(N_EDGES + 255) / 256, 256, 0, stream>>>(src, dst, cnt_out, cnt_in);
    scan_kernel<<<1, 1024, 0, stream>>>(cnt_in, cnt_out, row_ptr, cursor, rin, rout);
    transpose_kernel<<<(D * D + 255) / 256, 256, 0, stream>>>(W, Wr, Wt, Wrt);
    fill_kernel<<<(N_EDGES + 255) / 256, 256, 0, stream>>>(src, dst, cursor, csr_src);
    gemm_kernel<<<391, 256, 0, stream>>>(x, Wt, Wrt, br, rout, hw, out);
    agg_kernel<<<1024, 256, 0, stream>>>(hw, row_ptr, csr_src, rin, b, out, bn_part);
    bn_fin<<<1, 128, 0, stream>>>(bn_part, gamma, beta, scsh);
    norm_kernel<<<(N_NODES * 64) / 256, 256, 0, stream>>>(out, scsh);
}